// Round 3
// baseline (275.374 us; speedup 1.0000x reference)
//
#include <hip/hip_runtime.h>

// FeatureVolume: left/right [B=2, H=256, W=256, C=16] f32
// out [B, 2D=48, H, W, 2C=32] f32, disp = d-24, src_w = w-disp
// out[b,d,h,w, 0:16] = (0<=w-disp<W) ? left [b,h,w,:]      : 0
// out[b,d,h,w,16:32] = (0<=w-disp<W) ? right[b,h,w-disp,:] : 0
//
// Register-resident, LDS-free formulation. Thread g owns (b,h,w,c4q):
//   L = left[g], R = right[g]   (inputs are exactly 1 float4 per thread)
// per d:
//   A: out[d, w, c4q]        = valid(w,d) ? L : 0      (left half, all cols)
//   B: out[d, w, 4+c4q]      = 0          if !valid    (right-half border zeros)
//   C: out[d, w+disp, 4+c4q] = R          if dest in range (scatter; dest
//      validity == source-in-range == always true for our w)
// Coverage of the right half is exact & disjoint: B hits cols with src OOB,
// C hits cols with src in range.

#define MAXD 24
#define ND   48
#define HH   256
#define WW   256
#define SLICE_F4 (HH * WW * 8)   // float4s per (b,d) slice = 524288

__global__ __launch_bounds__(256) void FeatureVolume_68762426409246_kernel(
    const float4* __restrict__ left,
    const float4* __restrict__ right,
    float4* __restrict__ out) {
    const unsigned int g = blockIdx.x * 256u + threadIdx.x;   // 0..524287

    const float4 L = left[g];
    const float4 R = right[g];

    const unsigned int c4q = g & 3u;
    const unsigned int w   = (g >> 2) & 255u;
    const unsigned int h   = (g >> 10) & 255u;
    const unsigned int b   = g >> 18;

    // f4 index of (b, d=0, h, w, c4q) in out:
    unsigned long long baseA =
        (unsigned long long)(b * ND) * SLICE_F4 +
        (unsigned long long)((h * WW + w) * 8u + c4q);
    float4* pA = out + baseA;                 // left-half slot, marches over d
    float4* pC = pA + (-(int)MAXD * 8 + 4);   // right-half slot at col w+disp, d=0

    const float4 Z = make_float4(0.f, 0.f, 0.f, 0.f);

    int vA = (int)w + MAXD;   // = w - disp ; valid iff 0 <= vA < WW
    int vC = (int)w - MAXD;   // = w + disp ; scatter dest col

    #pragma unroll 4
    for (int d = 0; d < ND; ++d) {
        const bool valid = ((unsigned int)vA < (unsigned int)WW);

        pA[0] = valid ? L : Z;              // left half (incl. border zeros)
        if (!valid) pA[4] = Z;              // right-half border zeros
        if ((unsigned int)vC < (unsigned int)WW) pC[0] = R;  // right-half scatter

        pA += SLICE_F4;
        pC += SLICE_F4 + 8;                 // next slice, dest col shifts by +1
        vA -= 1;
        vC += 1;
    }
}

extern "C" void kernel_launch(void* const* d_in, const int* in_sizes, int n_in,
                              void* d_out, int out_size, void* d_ws, size_t ws_size,
                              hipStream_t stream) {
    const float4* left  = (const float4*)d_in[0];
    const float4* right = (const float4*)d_in[1];
    float4* out = (float4*)d_out;

    // one thread per input float4: 2*256*256*4 = 524288 threads
    FeatureVolume_68762426409246_kernel<<<2048, 256, 0, stream>>>(
        left, right, out);
}